// Round 5
// baseline (468.058 us; speedup 1.0000x reference)
//
#include <hip/hip_runtime.h>

#define NN 100000
#define NE 1600000
#define NG 1024
#define NODE_IN 163
#define SLOPE 0.01f
#define NBUK 391      // ceil(100000/256)
#define BUKSH 8       // 256 nodes per bucket
#define EPB 8192      // edges per partition block
#define NBLK ((NE + EPB - 1) / EPB)   // 196

// ---------------- CSR build (privatized counting sort; round-4, verified) -------------
__global__ void k_hist(const int* __restrict__ dst, int* __restrict__ bh, int E) {
  __shared__ int h[NBUK];
  for (int i = threadIdx.x; i < NBUK; i += 256) h[i] = 0;
  __syncthreads();
  int beg = blockIdx.x * EPB, end = min(E, beg + EPB);
  for (int e = beg + threadIdx.x; e < end; e += 256) atomicAdd(&h[dst[e] >> BUKSH], 1);
  __syncthreads();
  for (int i = threadIdx.x; i < NBUK; i += 256) bh[blockIdx.x * NBUK + i] = h[i];
}

__global__ void k_bucket_scan(int* __restrict__ bh, int* __restrict__ btot) {
  __shared__ int s[256];
  int bucket = blockIdx.x, tid = threadIdx.x;
  int v = (tid < NBLK) ? bh[tid * NBUK + bucket] : 0;
  s[tid] = v;
  __syncthreads();
  for (int off = 1; off < 256; off <<= 1) {
    int t = (tid >= off) ? s[tid - off] : 0;
    __syncthreads();
    s[tid] += t;
    __syncthreads();
  }
  if (tid < NBLK) bh[tid * NBUK + bucket] = s[tid] - v;
  if (tid == 255) btot[bucket] = s[255];
}

__global__ void k_btot_scan(const int* __restrict__ btot, int* __restrict__ boffs, int E) {
  __shared__ int s[512];
  int tid = threadIdx.x;
  int v = (tid < NBUK) ? btot[tid] : 0;
  s[tid] = v;
  __syncthreads();
  for (int off = 1; off < 512; off <<= 1) {
    int t = (tid >= off) ? s[tid - off] : 0;
    __syncthreads();
    s[tid] += t;
    __syncthreads();
  }
  if (tid < NBUK) boffs[tid] = s[tid] - v;
  if (tid == 0) boffs[NBUK] = E;
}

__global__ void k_scatter(const int* __restrict__ src, const int* __restrict__ dst,
                          const int* __restrict__ bh, const int* __restrict__ boffs,
                          unsigned* __restrict__ bedge, int E) {
  __shared__ int cur[NBUK];
  for (int i = threadIdx.x; i < NBUK; i += 256)
    cur[i] = boffs[i] + bh[blockIdx.x * NBUK + i];
  __syncthreads();
  int beg = blockIdx.x * EPB, end = min(E, beg + EPB);
  for (int e = beg + threadIdx.x; e < end; e += 256) {
    int d = dst[e];
    int pos = atomicAdd(&cur[d >> BUKSH], 1);
    bedge[pos] = (unsigned)src[e] | ((unsigned)(d & 255) << 17);
  }
}

__global__ void k_b2csr(const unsigned* __restrict__ bedge, const int* __restrict__ boffs,
                        int* __restrict__ offs, float* __restrict__ dis,
                        int* __restrict__ csr, int N) {
  __shared__ int lcnt[256];
  __shared__ int s[256];
  __shared__ int lcur[256];
  int b = blockIdx.x, tid = threadIdx.x;
  int beg = boffs[b], end = boffs[b + 1];
  lcnt[tid] = 0;
  __syncthreads();
  for (int e = beg + tid; e < end; e += 256) atomicAdd(&lcnt[bedge[e] >> 17], 1);
  __syncthreads();
  int v = lcnt[tid];
  s[tid] = v;
  __syncthreads();
  for (int off = 1; off < 256; off <<= 1) {
    int t = (tid >= off) ? s[tid - off] : 0;
    __syncthreads();
    s[tid] += t;
    __syncthreads();
  }
  int o = s[tid] - v;
  int node = (b << BUKSH) + tid;
  if (node <= N) offs[node] = beg + o;
  if (node < N) dis[node] = rsqrtf((float)(v + 1));
  lcur[tid] = o;
  __syncthreads();
  for (int e = beg + tid; e < end; e += 256) {
    unsigned w = bedge[e];
    int p = atomicAdd(&lcur[w >> 17], 1);
    csr[beg + p] = (int)(w & 0x1FFFFu);
  }
}

// ---------------- GEMM: lane=col, wave=16 rows, W resident in LDS, X dbuf -------------
template<int K> struct GP;
template<> struct GP<163> { static constexpr int KPAD = 164, NREG = 11; };
template<> struct GP<64>  { static constexpr int KPAD = 64,  NREG = 4;  };

template<int K>
__device__ __forceinline__ void gload(const float* __restrict__ X, int tile, int ntiles,
                                      int N, int tid, float4* rx) {
  if constexpr (K == 163) {
    int r = tid >> 2, jb = tid & 3;
    long gr = (long)tile * 64 + r;
    bool ok = (tile < ntiles) && (gr < (long)N);
    const float* xr = X + gr * 163;
    #pragma unroll
    for (int m = 0; m < 11; ++m) {
      int j = jb + 4 * m;
      float4 v = make_float4(0.f, 0.f, 0.f, 0.f);
      if (ok) {
        if (j < 40) v = *(const float4*)(xr + 4 * j);
        else if (j == 40) { v.x = xr[160]; v.y = xr[161]; v.z = xr[162]; }
      }
      rx[m] = v;
    }
  } else {
    bool tok = (tile < ntiles);
    const float4* xp = (const float4*)(X + (size_t)tile * 64 * 64);
    #pragma unroll
    for (int m = 0; m < 4; ++m) {
      int f = tid + 256 * m;
      int r = f >> 4;
      bool ok = tok && ((long)tile * 64 + r < (long)N);
      rx[m] = ok ? xp[f] : make_float4(0.f, 0.f, 0.f, 0.f);
    }
  }
}

template<int K>
__device__ __forceinline__ void lwrite(float* __restrict__ buf, int tid, const float4* rx) {
  if constexpr (K == 163) {
    int r = tid >> 2, jb = tid & 3;
    #pragma unroll
    for (int m = 0; m < 11; ++m) {
      int j = jb + 4 * m;
      if (j <= 40) *(float4*)(buf + r * 164 + 4 * j) = rx[m];
    }
  } else {
    float4* bp = (float4*)buf;
    #pragma unroll
    for (int m = 0; m < 4; ++m) bp[tid + 256 * m] = rx[m];
  }
}

template<int K>
__launch_bounds__(256)
__global__ void k_gemm(const float* __restrict__ X, const float* __restrict__ W,
                       const float* __restrict__ disv, float* __restrict__ Y,
                       int N, int ntiles) {
  constexpr int KPAD = GP<K>::KPAD;
  __shared__ float sW[KPAD * 64];
  __shared__ float sX[2][64 * KPAD];
  const int tid = threadIdx.x;
  const int lane = tid & 63;
  const int wv = tid >> 6;

  {  // stage W once (k-major; zero-pad rows K..KPAD)
    constexpr int totF4 = KPAD * 16;
    constexpr int srcF4 = (K * 64) / 4;
    for (int i = tid; i < totF4; i += 256) {
      float4 v = make_float4(0.f, 0.f, 0.f, 0.f);
      if (i < srcF4) v = ((const float4*)W)[i];
      ((float4*)sW)[i] = v;
    }
  }

  float4 rx[GP<K>::NREG];
  int tile = blockIdx.x;
  gload<K>(X, tile, ntiles, N, tid, rx);
  lwrite<K>(sX[0], tid, rx);
  __syncthreads();

  int cur = 0;
  while (tile < ntiles) {
    int nxt = tile + gridDim.x;
    gload<K>(X, nxt, ntiles, N, tid, rx);     // issue early (T14): latency hides under FMAs

    float acc[16];
    #pragma unroll
    for (int r = 0; r < 16; ++r) acc[r] = 0.f;
    const float* xw = sX[cur] + wv * 16 * KPAD;
    for (int k0 = 0; k0 < KPAD; k0 += 4) {
      float w0 = sW[(k0 + 0) * 64 + lane];
      float w1 = sW[(k0 + 1) * 64 + lane];
      float w2 = sW[(k0 + 2) * 64 + lane];
      float w3 = sW[(k0 + 3) * 64 + lane];
      #pragma unroll
      for (int r = 0; r < 16; ++r) {
        float4 xv = *(const float4*)(xw + r * KPAD + k0);   // uniform addr -> broadcast
        acc[r] += xv.x * w0;
        acc[r] += xv.y * w1;
        acc[r] += xv.z * w2;
        acc[r] += xv.w * w3;
      }
    }
    {
      long base = (long)tile * 64 + wv * 16;
      #pragma unroll
      for (int r = 0; r < 16; ++r) {
        long row = base + r;
        if (row < N) Y[row * 64 + lane] = acc[r] * disv[row];
      }
    }

    lwrite<K>(sX[cur ^ 1], tid, rx);          // write late
    __syncthreads();
    cur ^= 1;
    tile = nxt;
  }
}

// One wave per node: Hout[i] = lrelu( (Hps[i] + sum_{e->i} Hps[src]) * dis[i] + b )
__launch_bounds__(256)
__global__ void k_agg(const float* __restrict__ Hps, const int* __restrict__ offs,
                      const int* __restrict__ csr, const float* __restrict__ dis,
                      const float* __restrict__ bias, float* __restrict__ Hout, int N) {
  int node = blockIdx.x * 4 + (threadIdx.x >> 6);
  if (node >= N) return;
  int lane = threadIdx.x & 63;
  int beg = offs[node], end = offs[node + 1];
  float acc = Hps[(size_t)node * 64 + lane];
  int e = beg;
  for (; e + 4 <= end; e += 4) {
    int s0 = csr[e], s1 = csr[e + 1], s2 = csr[e + 2], s3 = csr[e + 3];
    acc += Hps[(size_t)s0 * 64 + lane];
    acc += Hps[(size_t)s1 * 64 + lane];
    acc += Hps[(size_t)s2 * 64 + lane];
    acc += Hps[(size_t)s3 * 64 + lane];
  }
  for (; e < end; ++e) acc += Hps[(size_t)csr[e] * 64 + lane];
  acc = acc * dis[node] + bias[lane];
  Hout[(size_t)node * 64 + lane] = (acc > 0.f) ? acc : SLOPE * acc;
}

// One wave per graph: mean-pool + fc1 + lrelu + fc2
__launch_bounds__(64)
__global__ void k_pool(const float* __restrict__ H, const int* __restrict__ batch,
                       const float* __restrict__ f1W, const float* __restrict__ f1b,
                       const float* __restrict__ f2W, const float* __restrict__ f2b,
                       float* __restrict__ out, int N) {
  int g = blockIdx.x;
  int lane = threadIdx.x;
  int lo = 0, hi = N;
  while (lo < hi) { int m = (lo + hi) >> 1; if (batch[m] < g) lo = m + 1; else hi = m; }
  int beg = lo;
  hi = N;
  while (lo < hi) { int m = (lo + hi) >> 1; if (batch[m] < g + 1) lo = m + 1; else hi = m; }
  int end = lo;
  float acc = 0.f;
  for (int r = beg; r < end; ++r) acc += H[(size_t)r * 64 + lane];
  float c = (float)(end - beg);
  acc /= (c < 1.f ? 1.f : c);
  __shared__ float p[64];
  p[lane] = acc;
  __syncthreads();
  float q = f1b[lane];
  #pragma unroll
  for (int k = 0; k < 64; ++k) q += p[k] * f1W[k * 64 + lane];
  q = (q > 0.f) ? q : SLOPE * q;
  float v = q * f2W[lane];
  #pragma unroll
  for (int off = 32; off > 0; off >>= 1) v += __shfl_down(v, off, 64);
  if (lane == 0) out[g] = v + f2b[0];
}

extern "C" void kernel_launch(void* const* d_in, const int* in_sizes, int n_in,
                              void* d_out, int out_size, void* d_ws, size_t ws_size,
                              hipStream_t stream) {
  const float* x    = (const float*)d_in[0];
  const int*  eidx  = (const int*)d_in[1];
  const int*  batch = (const int*)d_in[2];
  const float* W0 = (const float*)d_in[3];
  const float* b0 = (const float*)d_in[4];
  const float* W1 = (const float*)d_in[5];
  const float* b1 = (const float*)d_in[6];
  const float* W2 = (const float*)d_in[7];
  const float* b2 = (const float*)d_in[8];
  const float* f1W = (const float*)d_in[9];
  const float* f1b = (const float*)d_in[10];
  const float* f2W = (const float*)d_in[11];
  const float* f2b = (const float*)d_in[12];
  float* out = (float*)d_out;

  const int N = NN, E = NE;
  const int* src  = eidx;
  const int* dstp = eidx + E;

  const size_t NPAD = 100096;
  char* w = (char*)d_ws;
  float* bufA  = (float*)w; w += NPAD * 64 * 4;   // bedge aliases bufA (dead until gemm0)
  float* bufB  = (float*)w; w += NPAD * 64 * 4;
  int*   csr   = (int*)w;   w += (size_t)E * 4;
  int*   offs  = (int*)w;   w += (size_t)(N + 4) * 4;
  float* dis   = (float*)w; w += (size_t)N * 4;
  int*   bh    = (int*)w;   w += (size_t)NBLK * NBUK * 4;
  int*   btot  = (int*)w;   w += (NBUK + 1) * 4;
  int*   boffs = (int*)w;   w += (NBUK + 1) * 4;
  unsigned* bedge = (unsigned*)bufA;

  k_hist<<<NBLK, 256, 0, stream>>>(dstp, bh, E);
  k_bucket_scan<<<NBUK, 256, 0, stream>>>(bh, btot);
  k_btot_scan<<<1, 512, 0, stream>>>(btot, boffs, E);
  k_scatter<<<NBLK, 256, 0, stream>>>(src, dstp, bh, boffs, bedge, E);
  k_b2csr<<<NBUK, 256, 0, stream>>>(bedge, boffs, offs, dis, csr, N);

  const int NT = (N + 63) / 64;   // 1563
  k_gemm<NODE_IN><<<256, 256, 0, stream>>>(x, W0, dis, bufA, N, NT);
  k_agg<<<(N + 3) / 4, 256, 0, stream>>>(bufA, offs, csr, dis, b0, bufB, N);
  k_gemm<64><<<768, 256, 0, stream>>>(bufB, W1, dis, bufA, N, NT);
  k_agg<<<(N + 3) / 4, 256, 0, stream>>>(bufA, offs, csr, dis, b1, bufB, N);
  k_gemm<64><<<768, 256, 0, stream>>>(bufB, W2, dis, bufA, N, NT);
  k_agg<<<(N + 3) / 4, 256, 0, stream>>>(bufA, offs, csr, dis, b2, bufB, N);
  k_pool<<<NG, 64, 0, stream>>>(bufB, batch, f1W, f1b, f2W, f2b, out, N);
}